// Round 1
// baseline (170.866 us; speedup 1.0000x reference)
//
#include <hip/hip_runtime.h>
#include <cstddef>
#include <cstdint>

// Problem constants (CollectMerge): x (B, P*CO, HI, WI) fp32, loc (B, 2P, HO, WO) fp32,
// bias (CO) fp32 -> out (B, CO, HO, WO) fp32. Bilinear-sample each of P planes at loc,
// sum over P, add bias.
constexpr int B_  = 4;
constexpr int CO_ = 80;
constexpr int PN_ = 9;
constexpr int HI_ = 128;
constexpr int WI_ = 128;
constexpr int HW_ = HI_ * WI_;   // 16384

// ---------------------------------------------------------------------------
// Kernel 1: transpose x (B*P, CO, HW) -> xt (B*P, HW, CO)  [channel-last]
// so the 80-channel gather in kernel 2 reads contiguous 320B chunks.
// ---------------------------------------------------------------------------
__global__ __launch_bounds__(256) void transpose_k(const float* __restrict__ x,
                                                   float* __restrict__ xt) {
    const int bp  = blockIdx.y;          // 0 .. B*P-1
    const int hw0 = blockIdx.x << 6;     // 64 hw positions per block

    __shared__ float tile[CO_][65];      // +1 pad vs bank conflicts

    const float* src = x + (size_t)bp * CO_ * HW_ + hw0;
    for (int i = threadIdx.x; i < CO_ * 64; i += 256) {
        int co  = i >> 6;
        int hwl = i & 63;
        tile[co][hwl] = src[(size_t)co * HW_ + hwl];   // coalesced over hw
    }
    __syncthreads();

    float* dst = xt + ((size_t)bp * HW_ + hw0) * CO_;
    for (int i = threadIdx.x; i < 64 * CO_; i += 256) {
        int hwl = i / CO_;
        int co  = i - hwl * CO_;
        dst[i] = tile[co][hwl];                         // fully coalesced write
    }
}

// ---------------------------------------------------------------------------
// Kernel 2: gather + merge. One block handles (b, 16 consecutive output pixels).
// Phase A: 144 threads compute bilinear weights+indices per (p, pixel) into LDS.
// Phase B: 1280 work items (16 pix x 80 co), 5 per thread, channel-minor so the
//          xt gather is coalesced (consecutive lanes -> consecutive co).
// Phase C: re-layout through LDS so the channel-major output write is coalesced.
// ---------------------------------------------------------------------------
template <bool TR>
__global__ __launch_bounds__(256) void gather_k(const float* __restrict__ xsrc,
                                                const float* __restrict__ loc,
                                                const float* __restrict__ bias,
                                                float* __restrict__ out) {
    const int b   = blockIdx.x >> 10;          // HW/16 = 1024 blocks per batch
    const int hw0 = (blockIdx.x & 1023) << 4;  // 16 pixels per block
    const int tid = threadIdx.x;

    __shared__ float wts[PN_][16][4];
    __shared__ int   idxs[PN_][16][4];
    __shared__ float accs[16][CO_ + 1];

    // Phase A: weights/indices once per (p, pixel)
    if (tid < PN_ * 16) {
        const int p    = tid >> 4;
        const int pixl = tid & 15;
        const float y = loc[(((size_t)b * PN_ + p) * 2 + 0) * HW_ + hw0 + pixl];
        const float x = loc[(((size_t)b * PN_ + p) * 2 + 1) * HW_ + hw0 + pixl];
        const float y0f = floorf(y), x0f = floorf(x);
        const int   y0 = (int)y0f,  x0 = (int)x0f;
        const float dy = y - y0f,   dx = x - x0f;
        const float w[4] = { (1.f - dy) * (1.f - dx), (1.f - dy) * dx,
                             dy * (1.f - dx),         dy * dx };
#pragma unroll
        for (int c = 0; c < 4; ++c) {
            const int yi = y0 + (c >> 1);
            const int xi = x0 + (c & 1);
            const bool valid = (yi >= 0) & (yi < HI_) & (xi >= 0) & (xi < WI_);
            const int yc = min(max(yi, 0), HI_ - 1);
            const int xc = min(max(xi, 0), WI_ - 1);
            wts[p][pixl][c]  = valid ? w[c] : 0.f;
            idxs[p][pixl][c] = yc * WI_ + xc;
        }
    }
    __syncthreads();

    // Phase B: gather-accumulate, 5 items per thread
    float myacc[5];
    int   cos[5], pixls[5];
#pragma unroll
    for (int k = 0; k < 5; ++k) {
        const int item = tid + (k << 8);
        const int pixl = item / CO_;
        const int co   = item - pixl * CO_;
        cos[k] = co;
        pixls[k] = pixl;
        myacc[k] = bias[co];
    }

    for (int p = 0; p < PN_; ++p) {
        const float* base = TR ? (xsrc + ((size_t)b * PN_ + p) * HW_ * CO_)
                               : (xsrc + ((size_t)b * PN_ + p) * CO_ * HW_);
#pragma unroll
        for (int k = 0; k < 5; ++k) {
            const int co   = cos[k];
            const int pixl = pixls[k];
#pragma unroll
            for (int c = 0; c < 4; ++c) {
                const int   idx = idxs[p][pixl][c];
                const float w   = wts[p][pixl][c];
                const float v   = TR ? base[(size_t)idx * CO_ + co]
                                     : base[(size_t)co * HW_ + idx];
                myacc[k] = fmaf(v, w, myacc[k]);
            }
        }
    }

#pragma unroll
    for (int k = 0; k < 5; ++k) accs[pixls[k]][cos[k]] = myacc[k];
    __syncthreads();

    // Phase C: coalesced channel-major write
    for (int i = tid; i < 16 * CO_; i += 256) {
        const int co  = i >> 4;
        const int hwl = i & 15;
        out[((size_t)b * CO_ + co) * HW_ + hw0 + hwl] = accs[hwl][co];
    }
}

extern "C" void kernel_launch(void* const* d_in, const int* in_sizes, int n_in,
                              void* d_out, int out_size, void* d_ws, size_t ws_size,
                              hipStream_t stream) {
    const float* x    = (const float*)d_in[0];
    const float* loc  = (const float*)d_in[1];
    const float* bias = (const float*)d_in[2];
    float*       out  = (float*)d_out;

    const size_t need = (size_t)B_ * PN_ * CO_ * HW_ * sizeof(float);
    if (ws_size >= need) {
        float* xt = (float*)d_ws;
        dim3 g1(HW_ / 64, B_ * PN_);
        transpose_k<<<g1, 256, 0, stream>>>(x, xt);
        gather_k<true><<<dim3(B_ * HW_ / 16), 256, 0, stream>>>(xt, loc, bias, out);
    } else {
        // Workspace too small: direct (slower) path on the original layout.
        gather_k<false><<<dim3(B_ * HW_ / 16), 256, 0, stream>>>(x, loc, bias, out);
    }
}

// Round 2
// 111.668 us; speedup vs baseline: 1.5301x; 1.5301x over previous
//
#include <hip/hip_runtime.h>
#include <cstddef>
#include <cstdint>

// CollectMerge: x (B, P*CO, HI, WI) fp32, loc (B, 2P, HO, WO) fp32, bias (CO) fp32
// -> out (B, CO, HO, WO) fp32. Bilinear-sample each of P planes at loc, sum over P, + bias.
constexpr int B_  = 4;
constexpr int CO_ = 80;
constexpr int PN_ = 9;
constexpr int HI_ = 128;
constexpr int WI_ = 128;
constexpr int HW_ = HI_ * WI_;   // 16384

// ---------------------------------------------------------------------------
// Kernel 1: transpose+downconvert x (B*P, CO, HW) fp32 -> xt (B*P, HW, CO) bf16.
// Channel-last bf16: each gather sample is a contiguous 160B chunk, L3-resident
// (94.5 MB total).
// ---------------------------------------------------------------------------
__global__ __launch_bounds__(256) void transpose_bf16_k(const float* __restrict__ x,
                                                        uint16_t* __restrict__ xt) {
    const int bp  = blockIdx.y;          // 0 .. B*P-1
    const int hw0 = blockIdx.x << 6;     // 64 hw positions per block

    __shared__ uint16_t tile[CO_][65];   // pad 1: 2-row lane stride = 65 dwords -> conflict-free

    const float* src = x + (size_t)bp * CO_ * HW_ + hw0;
    for (int i = threadIdx.x; i < CO_ * 64; i += 256) {
        const int co  = i >> 6;
        const int hwl = i & 63;
        const uint32_t u = __float_as_uint(src[(size_t)co * HW_ + hwl]); // coalesced over hw
        const uint32_t r = (u + 0x7fffu + ((u >> 16) & 1u)) >> 16;       // RNE to bf16
        tile[co][hwl] = (uint16_t)r;
    }
    __syncthreads();

    // write 64 hw x 80 co bf16 = pack 2 channels per u32, fully coalesced
    uint32_t* dst = (uint32_t*)(xt + ((size_t)bp * HW_ + hw0) * CO_);
    for (int i = threadIdx.x; i < 64 * (CO_ / 2); i += 256) {
        const int hwl = i / 40;
        const int cp  = i - hwl * 40;
        const uint32_t lo = tile[2 * cp][hwl];
        const uint32_t hi = tile[2 * cp + 1][hwl];
        dst[hwl * 40 + cp] = lo | (hi << 16);
    }
}

// ---------------------------------------------------------------------------
// Kernel 2: gather + merge on bf16 channel-last xt.
// Block = 320 threads, 32 output pixels. Thread (pixl, cg): 8 channels via one
// 16B load per tap (10 lanes cover a 160B sample chunk, coalesced).
// ---------------------------------------------------------------------------
__global__ __launch_bounds__(320) void gather_bf16_k(const uint16_t* __restrict__ xt,
                                                     const float* __restrict__ loc,
                                                     const float* __restrict__ bias,
                                                     float* __restrict__ out) {
    const int b   = blockIdx.x >> 9;           // HW/32 = 512 blocks per batch
    const int hw0 = (blockIdx.x & 511) << 5;   // 32 pixels per block
    const int tid = threadIdx.x;

    __shared__ float wts[PN_][32][4];
    __shared__ int   idxs[PN_][32][4];
    __shared__ float accs[32][CO_ + 1];        // stride 81: odd -> conflict-free col reads

    // Phase A: bilinear weights/indices once per (p, pixel)
    if (tid < PN_ * 32) {
        const int p    = tid >> 5;
        const int pixl = tid & 31;
        const float y = loc[(((size_t)b * PN_ + p) * 2 + 0) * HW_ + hw0 + pixl];
        const float x = loc[(((size_t)b * PN_ + p) * 2 + 1) * HW_ + hw0 + pixl];
        const float y0f = floorf(y), x0f = floorf(x);
        const int   y0 = (int)y0f,  x0 = (int)x0f;
        const float dy = y - y0f,   dx = x - x0f;
        const float w[4] = { (1.f - dy) * (1.f - dx), (1.f - dy) * dx,
                             dy * (1.f - dx),         dy * dx };
#pragma unroll
        for (int c = 0; c < 4; ++c) {
            const int yi = y0 + (c >> 1);
            const int xi = x0 + (c & 1);
            const bool valid = (yi >= 0) & (yi < HI_) & (xi >= 0) & (xi < WI_);
            const int yc = min(max(yi, 0), HI_ - 1);
            const int xc = min(max(xi, 0), WI_ - 1);
            wts[p][pixl][c]  = valid ? w[c] : 0.f;
            idxs[p][pixl][c] = yc * WI_ + xc;
        }
    }
    __syncthreads();

    // Phase B: each thread owns (pixl, cg): pixel pixl, channels cg*8 .. cg*8+7
    const int pixl = tid / 10;
    const int cg   = tid - pixl * 10;

    float acc[8];
#pragma unroll
    for (int j = 0; j < 8; ++j) acc[j] = bias[cg * 8 + j];

    for (int p = 0; p < PN_; ++p) {
        const uint16_t* base = xt + ((size_t)b * PN_ + p) * (size_t)HW_ * CO_;
#pragma unroll
        for (int c = 0; c < 4; ++c) {
            const int   idx = idxs[p][pixl][c];
            const float w   = wts[p][pixl][c];
            const uint4 v = *(const uint4*)((const uint32_t*)(base + (size_t)idx * CO_) + cg * 4);
            const uint32_t us[4] = { v.x, v.y, v.z, v.w };
#pragma unroll
            for (int j = 0; j < 4; ++j) {
                const float f0 = __uint_as_float(us[j] << 16);
                const float f1 = __uint_as_float(us[j] & 0xffff0000u);
                acc[2 * j]     = fmaf(f0, w, acc[2 * j]);
                acc[2 * j + 1] = fmaf(f1, w, acc[2 * j + 1]);
            }
        }
    }

#pragma unroll
    for (int j = 0; j < 8; ++j) accs[pixl][cg * 8 + j] = acc[j];
    __syncthreads();

    // Phase C: coalesced channel-major write (32 consecutive hw per co row)
    for (int i = tid; i < 32 * CO_; i += 320) {
        const int co  = i >> 5;
        const int hwl = i & 31;
        out[((size_t)b * CO_ + co) * HW_ + hw0 + hwl] = accs[hwl][co];
    }
}

// ---------------------------------------------------------------------------
// Fallback (workspace too small): direct fp32 gather on original layout.
// ---------------------------------------------------------------------------
__global__ __launch_bounds__(256) void gather_direct_k(const float* __restrict__ xsrc,
                                                       const float* __restrict__ loc,
                                                       const float* __restrict__ bias,
                                                       float* __restrict__ out) {
    const int b   = blockIdx.x >> 10;
    const int hw0 = (blockIdx.x & 1023) << 4;
    const int tid = threadIdx.x;

    __shared__ float wts[PN_][16][4];
    __shared__ int   idxs[PN_][16][4];
    __shared__ float accs[16][CO_ + 1];

    if (tid < PN_ * 16) {
        const int p    = tid >> 4;
        const int pixl = tid & 15;
        const float y = loc[(((size_t)b * PN_ + p) * 2 + 0) * HW_ + hw0 + pixl];
        const float x = loc[(((size_t)b * PN_ + p) * 2 + 1) * HW_ + hw0 + pixl];
        const float y0f = floorf(y), x0f = floorf(x);
        const int   y0 = (int)y0f,  x0 = (int)x0f;
        const float dy = y - y0f,   dx = x - x0f;
        const float w[4] = { (1.f - dy) * (1.f - dx), (1.f - dy) * dx,
                             dy * (1.f - dx),         dy * dx };
#pragma unroll
        for (int c = 0; c < 4; ++c) {
            const int yi = y0 + (c >> 1);
            const int xi = x0 + (c & 1);
            const bool valid = (yi >= 0) & (yi < HI_) & (xi >= 0) & (xi < WI_);
            const int yc = min(max(yi, 0), HI_ - 1);
            const int xc = min(max(xi, 0), WI_ - 1);
            wts[p][pixl][c]  = valid ? w[c] : 0.f;
            idxs[p][pixl][c] = yc * WI_ + xc;
        }
    }
    __syncthreads();

    float myacc[5];
    int   cos[5], pixls[5];
#pragma unroll
    for (int k = 0; k < 5; ++k) {
        const int item = tid + (k << 8);
        const int pixl = item / CO_;
        const int co   = item - pixl * CO_;
        cos[k] = co; pixls[k] = pixl;
        myacc[k] = bias[co];
    }
    for (int p = 0; p < PN_; ++p) {
        const float* base = xsrc + ((size_t)b * PN_ + p) * CO_ * HW_;
#pragma unroll
        for (int k = 0; k < 5; ++k) {
#pragma unroll
            for (int c = 0; c < 4; ++c) {
                const int   idx = idxs[p][pixls[k]][c];
                const float w   = wts[p][pixls[k]][c];
                myacc[k] = fmaf(base[(size_t)cos[k] * HW_ + idx], w, myacc[k]);
            }
        }
    }
#pragma unroll
    for (int k = 0; k < 5; ++k) accs[pixls[k]][cos[k]] = myacc[k];
    __syncthreads();
    for (int i = tid; i < 16 * CO_; i += 256) {
        const int co  = i >> 4;
        const int hwl = i & 15;
        out[((size_t)b * CO_ + co) * HW_ + hw0 + hwl] = accs[hwl][co];
    }
}

extern "C" void kernel_launch(void* const* d_in, const int* in_sizes, int n_in,
                              void* d_out, int out_size, void* d_ws, size_t ws_size,
                              hipStream_t stream) {
    const float* x    = (const float*)d_in[0];
    const float* loc  = (const float*)d_in[1];
    const float* bias = (const float*)d_in[2];
    float*       out  = (float*)d_out;

    const size_t need = (size_t)B_ * PN_ * CO_ * HW_ * sizeof(uint16_t);
    if (ws_size >= need) {
        uint16_t* xt = (uint16_t*)d_ws;
        dim3 g1(HW_ / 64, B_ * PN_);
        transpose_bf16_k<<<g1, 256, 0, stream>>>(x, xt);
        gather_bf16_k<<<dim3(B_ * HW_ / 32), 320, 0, stream>>>(xt, loc, bias, out);
    } else {
        gather_direct_k<<<dim3(B_ * HW_ / 16), 256, 0, stream>>>(x, loc, bias, out);
    }
}